// Round 7
// baseline (1638.254 us; speedup 1.0000x reference)
//
#include <hip/hip_runtime.h>
#include <math.h>

typedef _Float16 f16x8 __attribute__((ext_vector_type(8)));
typedef float    f32x16 __attribute__((ext_vector_type(16)));

#define DEVINL __device__ __forceinline__

DEVINL float fast_sigmoid(float x) {
    x = fminf(fmaxf(x, -30.f), 30.f);
    return 1.0f / (1.0f + __expf(-x));
}
DEVINL float fast_tanh(float x) {
    x = fminf(fmaxf(x, -15.f), 15.f);
    float e = __expf(-2.f * x);
    return (1.f - e) / (1.f + e);
}
DEVINL f16x8 f16x8_zero() {
    f16x8 v;
    #pragma unroll
    for (int j = 0; j < 8; ++j) v[j] = (_Float16)0.f;
    return v;
}
DEVINL int aload_agent(const int* p) {
    return __hip_atomic_load(p, __ATOMIC_ACQUIRE, __HIP_MEMORY_SCOPE_AGENT);
}

#define TKY(t) ((t) < 25 ? (t) / 5 : 2)
#define TKX(t) ((t) < 25 ? (t) % 5 : 2)

// ---------------------------------------------------------------------------
// kT_prep: weight repack (unchanged from round 4/5).
// ---------------------------------------------------------------------------
__global__ void kT_prep(const float* __restrict__ w1, const float* __restrict__ w2,
                        const float* __restrict__ wx, const float* __restrict__ wh,
                        const float* __restrict__ bx, const float* __restrict__ bh,
                        float* __restrict__ w1T, _Float16* __restrict__ w2F,
                        _Float16* __restrict__ wxF, _Float16* __restrict__ whF,
                        float* __restrict__ btot)
{
    int t = blockIdx.x * 256 + threadIdx.x;
    int stride = gridDim.x * 256;
    for (int i = t; i < 100; i += stride) {
        int oc = i / 25, k = i % 25;
        w1T[k * 4 + oc] = w1[i];
    }
    for (int i = t; i < 12 * 512; i += stride) {      // w2F
        int j = i & 7, l = (i >> 3) & 63, q = i >> 9;
        int g = l >> 5, m = l & 31;
        int k = q * 16 + g * 8 + j;
        int pr = k >> 5, pc = (k >> 2) & 7, ic = k & 3;
        float v = 0.f;
        if (m < 16) {
            int oc = m >> 2, qy = (m >> 1) & 1, qx = m & 1;
            int ky = pr - qy, kx = pc - qx;
            if ((unsigned)ky < 5u && (unsigned)kx < 5u)
                v = w2[(oc * 4 + ic) * 25 + ky * 5 + kx];
        }
        w2F[i] = (_Float16)v;
    }
    for (int i = t; i < 10 * 512; i += stride) {      // wxF
        int j = i & 7, l = (i >> 3) & 63, q = i >> 9;
        int g = l >> 5, m = l & 31;
        int k = q * 16 + g * 8 + j;
        int pr = k >> 5, pc = (k >> 2) & 7, ic = k & 3;
        int og = (m & 3) * 8 + (m >> 2);
        float v = (pr < 5 && pc < 5) ? wx[(og * 4 + ic) * 25 + pr * 5 + pc] : 0.f;
        wxF[i] = (_Float16)v;
    }
    for (int i = t; i < 14 * 512; i += stride) {      // whF
        int j = i & 7, l = (i >> 3) & 63, q = i >> 9;
        int g = l >> 5, m = l & 31;
        int og = (m & 3) * 8 + (m >> 2);
        int tap = 2 * q + g;
        float v = (tap < 25) ? wh[(og * 8 + j) * 25 + tap] : 0.f;
        whF[i] = (_Float16)v;
    }
    if (t < 32) {
        int og = (t & 3) * 8 + (t >> 2);
        btot[t] = bx[og] + bh[og];
    }
}

// ---------------------------------------------------------------------------
// k1: conv 1->4 + relu + maxpool2 (VALU, LDS-staged), (256,4) bounds.
// ---------------------------------------------------------------------------
__global__ __launch_bounds__(256, 4) void k1_conv_pool(
    const float* __restrict__ obs, const float* __restrict__ w1T,
    const float* __restrict__ b1, _Float16* __restrict__ s1cl)
{
    __shared__ float lds[12 * 260];
    int tid = threadIdx.x;
    int yt = blockIdx.x & 31;
    int tb = blockIdx.x >> 5;

    const float* in = obs + ((size_t)tb << 16);
    for (int i = tid; i < 12 * 130; i += 256) {
        int r = i / 130, c2 = i % 130;
        int gy = (yt << 3) - 2 + r;
        int gx = 2 * c2 - 2;
        float2 v = make_float2(0.f, 0.f);
        if ((unsigned)gy < 256u && (unsigned)gx < 255u)
            v = *(const float2*)(in + (gy << 8) + gx);
        lds[r * 260 + 2 * c2]     = v.x;
        lds[r * 260 + 2 * c2 + 1] = v.y;
    }
    __syncthreads();

    int ly  = tid >> 6;
    int px0 = 2 * (tid & 63);
    int r0 = 2 * ly;
    int c0 = 2 * px0;

    float p[6][8];
    #pragma unroll
    for (int r = 0; r < 6; ++r) {
        #pragma unroll
        for (int c4 = 0; c4 < 2; ++c4) {
            float4 v = *(const float4*)&lds[(r0 + r) * 260 + c0 + 4 * c4];
            p[r][4 * c4 + 0] = v.x; p[r][4 * c4 + 1] = v.y;
            p[r][4 * c4 + 2] = v.z; p[r][4 * c4 + 3] = v.w;
        }
    }

    f16x8 outv;
    #pragma unroll
    for (int oc = 0; oc < 4; ++oc) {
        float bias = b1[oc];
        float m0 = 0.f, m1 = 0.f;
        #pragma unroll
        for (int pp = 0; pp < 2; ++pp)
        #pragma unroll
        for (int q = 0; q < 2; ++q) {
            float a0 = bias, a1 = bias;
            #pragma unroll
            for (int ky = 0; ky < 5; ++ky)
            #pragma unroll
            for (int kx = 0; kx < 5; ++kx) {
                float w = w1T[(ky * 5 + kx) * 4 + oc];
                a0 = fmaf(p[pp + ky][q + kx],     w, a0);
                a1 = fmaf(p[pp + ky][q + kx + 2], w, a1);
            }
            m0 = fmaxf(m0, a0);
            m1 = fmaxf(m1, a1);
        }
        outv[oc]     = (_Float16)m0;
        outv[oc + 4] = (_Float16)m1;
    }
    int gyp = (yt << 2) + ly;
    *(f16x8*)(s1cl + ((((size_t)tb << 14) + (gyp << 7) + px0) << 2)) = outv;
}

// ---------------------------------------------------------------------------
// k2: conv 4->4 + relu + maxpool2 as MFMA (pool folded into M). Unchanged.
// ---------------------------------------------------------------------------
__global__ __launch_bounds__(256) void k2_mfma(
    const _Float16* __restrict__ s1cl, const _Float16* __restrict__ w2F,
    const float* __restrict__ b2, _Float16* __restrict__ s2cl)
{
    __shared__ _Float16 lds[20 * 136 * 4];
    int tid = threadIdx.x;
    int lane = tid & 63, w = tid >> 6, g = lane >> 5;
    int f  = blockIdx.x >> 3;
    int yt = blockIdx.x & 7;
    int y0 = yt << 3;

    f16x8 wf[12];
    #pragma unroll
    for (int q = 0; q < 12; ++q)
        wf[q] = *(const f16x8*)(w2F + ((size_t)q * 64 + lane) * 8);

    float bA = b2[g], bB = b2[g + 2];

    for (int i = tid; i < 20 * 68; i += 256) {
        int r = i / 68, u = i % 68;
        int gy = (yt << 4) - 2 + r;
        int gx = 2 * u - 2;
        f16x8 v = f16x8_zero();
        if ((unsigned)gy < 128u && (unsigned)gx < 127u)
            v = *(const f16x8*)(s1cl + ((((size_t)f << 14) + (gy << 7) + gx) << 2));
        *(f16x8*)&lds[(r * 136 + 2 * u) * 4] = v;
    }
    __syncthreads();

    #pragma unroll
    for (int i = 0; i < 4; ++i) {
        int ct = w * 4 + i;
        int ly = ct >> 1, hx = ct & 1;
        int px = hx * 32 + (lane & 31);
        int base = (2 * ly) * 1088 + (2 * px) * 8 + g * 16;

        f32x16 acc;
        #pragma unroll
        for (int r = 0; r < 16; ++r) acc[r] = 0.f;

        #pragma unroll
        for (int q = 0; q < 12; ++q) {
            f16x8 bv = *(const f16x8*)((const char*)lds + base +
                                       ((q >> 1) * 1088 + (q & 1) * 32));
            acc = __builtin_amdgcn_mfma_f32_32x32x16_f16(wf[q], bv, acc, 0, 0, 0);
        }

        float mA = fmaxf(fmaxf(fmaxf(acc[0], acc[1]), fmaxf(acc[2], acc[3])) + bA, 0.f);
        float mB = fmaxf(fmaxf(fmaxf(acc[4], acc[5]), fmaxf(acc[6], acc[7])) + bB, 0.f);

        int pix = ((y0 + ly) << 6) + px;
        _Float16* dst = s2cl + ((((size_t)f << 12) + pix) << 2);
        dst[g]     = (_Float16)mA;
        dst[g + 2] = (_Float16)mB;
    }
}

// ---------------------------------------------------------------------------
// k3: conv 4->32 gate precompute, MFMA -> xg f16 fragment layout. Unchanged.
// ---------------------------------------------------------------------------
__global__ __launch_bounds__(256) void k3_mfma(
    const _Float16* __restrict__ s2cl, const _Float16* __restrict__ wxF,
    const float* __restrict__ btot, _Float16* __restrict__ xg)
{
    __shared__ _Float16 lds[12 * 72 * 4];
    int tid = threadIdx.x;
    int lane = tid & 63, w = tid >> 6, g = lane >> 5;
    int f  = blockIdx.x >> 3;
    int yt = blockIdx.x & 7;
    int y0 = yt << 3;

    f16x8 wf[10];
    #pragma unroll
    for (int q = 0; q < 10; ++q)
        wf[q] = *(const f16x8*)(wxF + ((size_t)q * 64 + lane) * 8);

    float bsel[16];
    #pragma unroll
    for (int r = 0; r < 16; ++r) {
        int row0 = (r & 3) + 8 * (r >> 2);
        bsel[r] = g ? btot[row0 + 4] : btot[row0];
    }

    for (int i = tid; i < 12 * 36; i += 256) {
        int r = i / 36, u = i % 36;
        int gy = y0 - 2 + r;
        int gx = 2 * u - 2;
        f16x8 v = f16x8_zero();
        if ((unsigned)gy < 64u && (unsigned)gx < 63u)
            v = *(const f16x8*)(s2cl + ((((size_t)f << 12) + (gy << 6) + gx) << 2));
        *(f16x8*)&lds[(r * 72 + 2 * u) * 4] = v;
    }
    __syncthreads();

    #pragma unroll
    for (int i = 0; i < 4; ++i) {
        int ct = w * 4 + i;
        int ly = ct >> 1, hx = ct & 1;
        int px = hx * 32 + (lane & 31);
        int base = ly * 576 + px * 8 + g * 16;

        f32x16 acc;
        #pragma unroll
        for (int r = 0; r < 16; ++r) acc[r] = 0.f;

        #pragma unroll
        for (int q = 0; q < 10; ++q) {
            f16x8 bv = *(const f16x8*)((const char*)lds + base +
                                       ((q >> 1) * 576 + (q & 1) * 32));
            acc = __builtin_amdgcn_mfma_f32_32x32x16_f16(wf[q], bv, acc, 0, 0, 0);
        }

        size_t tl = (size_t)f * 128 + (y0 + ly) * 2 + hx;
        f16x8 lo, hi;
        #pragma unroll
        for (int r = 0; r < 8; ++r) {
            lo[r] = (_Float16)(acc[r] + bsel[r]);
            hi[r] = (_Float16)(acc[r + 8] + bsel[r + 8]);
        }
        _Float16* dst = xg + tl * 1024 + lane * 16;
        *(f16x8*)dst       = lo;
        *(f16x8*)(dst + 8) = hi;
    }
}

// ---------------------------------------------------------------------------
// kc_lstm2: ALL 8 ConvLSTM steps, persistent kernel with NEIGHBOR-FLAG sync
//   (no grid.sync — round 6 measured ~195us per grid barrier).
//   1024 blocks x 256 thr, cooperative launch only for co-residency.
//   Block owns (b, 2 rows). Per step, halo = +-2 rows = adjacent blocks only:
//   wait flags[bid+-1] >= t (acquire), compute, write h rows, threadfence
//   (release), publish flags[bid] = t+1. Ping-pong h buffers: neighbor flag
//   >= t guarantees it finished READING buffer t&1, so t+2 overwrite is safe.
//   c + peepholes + whF fragments live in registers for all 8 steps.
// ---------------------------------------------------------------------------
__global__ __launch_bounds__(256, 4) void kc_lstm2(
    const _Float16* __restrict__ xg, _Float16* __restrict__ hbuf,
    const _Float16* __restrict__ whF,
    const float* __restrict__ wci, const float* __restrict__ wcf,
    const float* __restrict__ wco, float* __restrict__ out_hc,
    int* __restrict__ flags)
{
    __shared__ _Float16 lds[6 * 68 * 8];     // pitch 1088 B/row
    int tid = threadIdx.x;
    int lane = tid & 63, w = tid >> 6, g = lane >> 5;
    int bid = blockIdx.x;
    int b   = bid >> 5;
    int yt  = bid & 31;
    int y0  = yt << 1;

    f16x8 wf[14];
    #pragma unroll
    for (int q = 0; q < 14; ++q)
        wf[q] = *(const f16x8*)(whF + ((size_t)q * 64 + lane) * 8);

    int toffs[14];
    #pragma unroll
    for (int q = 0; q < 14; ++q) {
        int t0 = 2 * q, t1 = 2 * q + 1;
        int o0 = TKY(t0) * 1088 + TKX(t0) * 16;
        int o1 = TKY(t1) * 1088 + TKX(t1) * 16;
        toffs[q] = g ? o1 : o0;
    }

    int ly = w >> 1, hx = w & 1;
    int px = hx * 32 + (lane & 31);
    int pix = ((y0 + ly) << 6) + px;
    size_t tl = (size_t)b * 128 + (y0 + ly) * 2 + hx;
    int base = ly * 1088 + px * 16;

    float creg[4] = {0.f, 0.f, 0.f, 0.f};
    float pci[4], pcf[4], pco[4];
    #pragma unroll
    for (int cc = 0; cc < 4; ++cc) {
        int ppix = ((2 * cc + g) << 12) + pix;
        pci[cc] = wci[ppix];
        pcf[cc] = wcf[ppix];
        pco[cc] = wco[ppix];
    }

    for (int t = 0; t < 8; ++t) {
        if (t > 0) {
            // acquire: neighbors must have finished step t-1 (published t)
            if (tid == 0 && yt > 0)
                while (aload_agent(flags + bid - 1) < t)
                    __builtin_amdgcn_s_sleep(8);
            if (tid == 1 && yt < 31)
                while (aload_agent(flags + bid + 1) < t)
                    __builtin_amdgcn_s_sleep(8);
            __syncthreads();
            __threadfence();
        }

        const _Float16* hprev = hbuf + (size_t)(t & 1) * 1048576;
        _Float16*       hnext = hbuf + (size_t)((t + 1) & 1) * 1048576;

        for (int i = tid; i < 6 * 68; i += 256) {
            int r = i / 68, u = i % 68;
            int gy = y0 - 2 + r;
            int gx = u - 2;
            f16x8 v = f16x8_zero();
            if ((unsigned)gy < 64u && (unsigned)gx < 64u)
                v = *(const f16x8*)(hprev +
                        ((((size_t)b << 12) + (gy << 6) + gx) << 3));
            *(f16x8*)&lds[(r * 68 + u) * 8] = v;
        }
        __syncthreads();

        const f16x8* xs = (const f16x8*)(xg + (size_t)t * 4194304 +
                                         tl * 1024 + lane * 16);
        f16x8 v0 = xs[0], v1 = xs[1];
        f32x16 acc;
        #pragma unroll
        for (int r = 0; r < 8; ++r) {
            acc[r]     = (float)v0[r];
            acc[r + 8] = (float)v1[r];
        }

        #pragma unroll
        for (int q = 0; q < 14; ++q) {
            f16x8 bv = *(const f16x8*)((const char*)lds + base + toffs[q]);
            acc = __builtin_amdgcn_mfma_f32_32x32x16_f16(wf[q], bv, acc, 0, 0, 0);
        }

        #pragma unroll
        for (int cc = 0; cc < 4; ++cc) {
            float c_old = creg[cc];
            float i_ = fast_sigmoid(acc[4 * cc + 0] + c_old * pci[cc]);
            float f_ = fast_sigmoid(acc[4 * cc + 1] + c_old * pcf[cc]);
            float cn = f_ * c_old + i_ * fast_tanh(acc[4 * cc + 2]);
            float o_ = fast_sigmoid(acc[4 * cc + 3] + cn * pco[cc]);
            float hn = o_ * fast_tanh(cn);
            creg[cc] = cn;
            int ch = 2 * cc + g;
            if (t == 7) {
                size_t sidx = (((size_t)b * 8 + ch) << 12) + pix;
                out_hc[sidx] = hn;
                out_hc[sidx + 1048576] = cn;
            } else {
                hnext[((((size_t)b << 12) + pix) << 3) + ch] = (_Float16)hn;
            }
        }

        if (t < 7) {
            __threadfence();     // release: h writes visible device-wide
            __syncthreads();     // all threads in block done (also fences LDS reuse)
            if (tid == 0)
                __hip_atomic_store(flags + bid, t + 1, __ATOMIC_RELEASE,
                                   __HIP_MEMORY_SCOPE_AGENT);
        }
    }
}

// ---------------------------------------------------------------------------
// k4_mfma: single-step fallback (used only if cooperative launch fails).
// ---------------------------------------------------------------------------
__global__ __launch_bounds__(256) void k4_mfma(
    const _Float16* __restrict__ xg_t, const _Float16* __restrict__ hprev,
    const _Float16* __restrict__ whF, float* __restrict__ cbuf,
    const float* __restrict__ wci, const float* __restrict__ wcf,
    const float* __restrict__ wco, _Float16* __restrict__ hnext,
    float* __restrict__ out_hc, int last)
{
    __shared__ _Float16 lds[6 * 68 * 8];
    int tid = threadIdx.x;
    int lane = tid & 63, w = tid >> 6, g = lane >> 5;
    int b  = blockIdx.x >> 5;
    int y0 = (blockIdx.x & 31) << 1;

    f16x8 wf[14];
    #pragma unroll
    for (int q = 0; q < 14; ++q)
        wf[q] = *(const f16x8*)(whF + ((size_t)q * 64 + lane) * 8);

    for (int i = tid; i < 6 * 68; i += 256) {
        int r = i / 68, u = i % 68;
        int gy = y0 - 2 + r;
        int gx = u - 2;
        f16x8 v = f16x8_zero();
        if ((unsigned)gy < 64u && (unsigned)gx < 64u)
            v = *(const f16x8*)(hprev + ((((size_t)b << 12) + (gy << 6) + gx) << 3));
        *(f16x8*)&lds[(r * 68 + u) * 8] = v;
    }
    __syncthreads();

    int toffs[14];
    #pragma unroll
    for (int q = 0; q < 14; ++q) {
        int t0 = 2 * q, t1 = 2 * q + 1;
        int o0 = TKY(t0) * 1088 + TKX(t0) * 16;
        int o1 = TKY(t1) * 1088 + TKX(t1) * 16;
        toffs[q] = g ? o1 : o0;
    }

    int ly = w >> 1, hx = w & 1;
    int px = hx * 32 + (lane & 31);
    size_t tl = (size_t)b * 128 + (y0 + ly) * 2 + hx;

    const f16x8* xs = (const f16x8*)(xg_t + tl * 1024 + lane * 16);
    f16x8 v0 = xs[0], v1 = xs[1];
    f32x16 acc;
    #pragma unroll
    for (int r = 0; r < 8; ++r) {
        acc[r]     = (float)v0[r];
        acc[r + 8] = (float)v1[r];
    }

    int base = ly * 1088 + px * 16;
    #pragma unroll
    for (int q = 0; q < 14; ++q) {
        f16x8 bv = *(const f16x8*)((const char*)lds + base + toffs[q]);
        acc = __builtin_amdgcn_mfma_f32_32x32x16_f16(wf[q], bv, acc, 0, 0, 0);
    }

    int pix = ((y0 + ly) << 6) + px;
    #pragma unroll
    for (int cc = 0; cc < 4; ++cc) {
        int ch = 2 * cc + g;
        size_t sidx = (((size_t)b * 8 + ch) << 12) + pix;
        int ppix = (ch << 12) + pix;
        float c_old = cbuf[sidx];
        float i_ = fast_sigmoid(acc[4 * cc + 0] + c_old * wci[ppix]);
        float f_ = fast_sigmoid(acc[4 * cc + 1] + c_old * wcf[ppix]);
        float cn = f_ * c_old + i_ * fast_tanh(acc[4 * cc + 2]);
        float o_ = fast_sigmoid(acc[4 * cc + 3] + cn * wco[ppix]);
        float hn = o_ * fast_tanh(cn);
        if (last) {
            out_hc[sidx] = hn;
            out_hc[sidx + 1048576] = cn;
        } else {
            cbuf[sidx] = cn;
            hnext[((((size_t)b << 12) + pix) << 3) + ch] = (_Float16)hn;
        }
    }
}

// ---------------------------------------------------------------------------
extern "C" void kernel_launch(void* const* d_in, const int* in_sizes, int n_in,
                              void* d_out, int out_size, void* d_ws, size_t ws_size,
                              hipStream_t stream)
{
    const float* obs = (const float*)d_in[0];
    const float* w1  = (const float*)d_in[1];
    const float* b1  = (const float*)d_in[2];
    const float* w2  = (const float*)d_in[3];
    const float* b2  = (const float*)d_in[4];
    const float* wx  = (const float*)d_in[5];
    const float* bx  = (const float*)d_in[6];
    const float* wh  = (const float*)d_in[7];
    const float* bh  = (const float*)d_in[8];
    const float* wci = (const float*)d_in[9];
    const float* wcf = (const float*)d_in[10];
    const float* wco = (const float*)d_in[11];

    char* wsb = (char*)d_ws;
    // byte layout:
    //   [0, 67,108,864)             xg f16 (overlays s1cl, dead after k2)
    //   [67,108,864, 75,497,472)    s2cl f16 [256][4096][4]
    //   [75,497,472, 79,691,776)    hA | hB f16 (1,048,576 f16 each)
    //   [79,691,776, 83,886,080)    cbuf f32 (fallback only)
    //   [83,886,080, ...)           w1T, w2F, wxF, whF, btot, flags
    _Float16* xg   = (_Float16*)wsb;
    _Float16* s1cl = (_Float16*)wsb;
    _Float16* s2cl = (_Float16*)(wsb + 67108864);
    _Float16* hAB  = (_Float16*)(wsb + 75497472);
    float*    cbuf = (float*)(wsb + 79691776);
    float*    w1T  = (float*)(wsb + 83886080);
    _Float16* w2F  = (_Float16*)(wsb + 83886592);
    _Float16* wxF  = (_Float16*)(wsb + 83898880);
    _Float16* whF  = (_Float16*)(wsb + 83909120);
    float*    btot = (float*)(wsb + 83923456);
    int*      flags= (int*)(wsb + 83923584);

    kT_prep<<<64, 256, 0, stream>>>(w1, w2, wx, wh, bx, bh,
                                    w1T, w2F, wxF, whF, btot);

    k1_conv_pool<<<8192, 256, 0, stream>>>(obs, w1T, b1, s1cl);
    k2_mfma     <<<2048, 256, 0, stream>>>(s1cl, w2F, b2, s2cl);
    k3_mfma     <<<2048, 256, 0, stream>>>(s2cl, wxF, btot, xg);

    hipMemsetAsync(hAB, 0, 2097152, stream);   // zero hA (t=0 reads it)
    hipMemsetAsync(flags, 0, 4096, stream);    // reset sync flags

    float* outp = (float*)d_out;
    void* args[] = {(void*)&xg, (void*)&hAB, (void*)&whF,
                    (void*)&wci, (void*)&wcf, (void*)&wco,
                    (void*)&outp, (void*)&flags};
    hipError_t err = hipLaunchCooperativeKernel(
        (const void*)kc_lstm2, dim3(1024), dim3(256), args, 0, stream);

    if (err != hipSuccess) {
        // fallback: 8 single-step launches with c in global f32
        hipMemsetAsync(cbuf, 0, 4194304, stream);
        _Float16* hA = hAB;
        _Float16* hB = hAB + 1048576;
        for (int t = 0; t < 8; ++t) {
            const _Float16* hp = (t & 1) ? hB : hA;
            _Float16*       hn = (t & 1) ? hA : hB;
            k4_mfma<<<1024, 256, 0, stream>>>(
                xg + (size_t)t * 4194304, hp, whF, cbuf,
                wci, wcf, wco, hn, outp, t == 7);
        }
    }
}

// Round 8
// 149.043 us; speedup vs baseline: 10.9918x; 10.9918x over previous
//
#include <hip/hip_runtime.h>
#include <math.h>

typedef _Float16 f16x8 __attribute__((ext_vector_type(8)));
typedef _Float16 f16x4 __attribute__((ext_vector_type(4)));
typedef float    f32x16 __attribute__((ext_vector_type(16)));
typedef unsigned int u32;

#define DEVINL __device__ __forceinline__

DEVINL float fast_sigmoid(float x) {
    x = fminf(fmaxf(x, -30.f), 30.f);
    return 1.0f / (1.0f + __expf(-x));
}
DEVINL float fast_tanh(float x) {
    x = fminf(fmaxf(x, -15.f), 15.f);
    float e = __expf(-2.f * x);
    return (1.f - e) / (1.f + e);
}
DEVINL f16x8 f16x8_zero() {
    f16x8 v;
    #pragma unroll
    for (int j = 0; j < 8; ++j) v[j] = (_Float16)0.f;
    return v;
}

#define TKY(t) ((t) < 25 ? (t) / 5 : 2)
#define TKX(t) ((t) < 25 ? (t) % 5 : 2)

// ---------------------------------------------------------------------------
// kT_prep: weight repack + state zero-init (folded memsets).
//  wk1F [3][64][8]  f16: k1 A-frags (32x32x16; m=oc*4+pos<16, pr=2q+g, pc=j)
//  w2F  [12][64][8] f16: k2 A-frags (pool-in-M, K=(pr,pc,ic))
//  wxF  [10][64][8] f16: k3 A-frags (m=ch*4+gate, K=(pr,pc,ic))
//  whF  [14][64][8] f16: k4 A-frags, tap-pair; j indexes ch' = cc+4*g order
//  btot[m] = bx[og]+bh[og];  cfr (1M f32) and hA (1M f16) zeroed here.
// ---------------------------------------------------------------------------
__global__ void kT_prep(const float* __restrict__ w1, const float* __restrict__ w2,
                        const float* __restrict__ wx, const float* __restrict__ wh,
                        const float* __restrict__ bx, const float* __restrict__ bh,
                        _Float16* __restrict__ wk1F, _Float16* __restrict__ w2F,
                        _Float16* __restrict__ wxF, _Float16* __restrict__ whF,
                        float* __restrict__ btot,
                        float* __restrict__ cfr, _Float16* __restrict__ hA)
{
    int t = blockIdx.x * 256 + threadIdx.x;
    int stride = gridDim.x * 256;

    for (int i = t; i < 3 * 512; i += stride) {       // wk1F
        int j = i & 7, l = (i >> 3) & 63, q = i >> 9;
        int g = l >> 5, m = l & 31;
        int pr = 2 * q + g, pc = j;
        float v = 0.f;
        if (m < 16) {
            int oc = m >> 2, qy = (m >> 1) & 1, qx = m & 1;
            int ky = pr - qy, kx = pc - qx;
            if ((unsigned)ky < 5u && (unsigned)kx < 5u)
                v = w1[oc * 25 + ky * 5 + kx];
        }
        wk1F[i] = (_Float16)v;
    }
    for (int i = t; i < 12 * 512; i += stride) {      // w2F
        int j = i & 7, l = (i >> 3) & 63, q = i >> 9;
        int g = l >> 5, m = l & 31;
        int k = q * 16 + g * 8 + j;
        int pr = k >> 5, pc = (k >> 2) & 7, ic = k & 3;
        float v = 0.f;
        if (m < 16) {
            int oc = m >> 2, qy = (m >> 1) & 1, qx = m & 1;
            int ky = pr - qy, kx = pc - qx;
            if ((unsigned)ky < 5u && (unsigned)kx < 5u)
                v = w2[(oc * 4 + ic) * 25 + ky * 5 + kx];
        }
        w2F[i] = (_Float16)v;
    }
    for (int i = t; i < 10 * 512; i += stride) {      // wxF
        int j = i & 7, l = (i >> 3) & 63, q = i >> 9;
        int g = l >> 5, m = l & 31;
        int k = q * 16 + g * 8 + j;
        int pr = k >> 5, pc = (k >> 2) & 7, ic = k & 3;
        int og = (m & 3) * 8 + (m >> 2);
        float v = (pr < 5 && pc < 5) ? wx[(og * 4 + ic) * 25 + pr * 5 + pc] : 0.f;
        wxF[i] = (_Float16)v;
    }
    for (int i = t; i < 14 * 512; i += stride) {      // whF (j = ch' order)
        int j = i & 7, l = (i >> 3) & 63, q = i >> 9;
        int g = l >> 5, m = l & 31;
        int og = (m & 3) * 8 + (m >> 2);
        int tap = 2 * q + g;
        int icj = 2 * (j & 3) + (j >> 2);             // ch' -> real channel
        float v = (tap < 25) ? wh[(og * 8 + icj) * 25 + tap] : 0.f;
        whF[i] = (_Float16)v;
    }
    if (t < 32) {
        int og = (t & 3) * 8 + (t >> 2);
        btot[t] = bx[og] + bh[og];
    }
    float4 z4 = make_float4(0.f, 0.f, 0.f, 0.f);
    for (int i = t; i < 262144; i += stride) ((float4*)cfr)[i] = z4;  // 4MB
    for (int i = t; i < 131072; i += stride) ((float4*)hA)[i]  = z4;  // 2MB
}

// ---------------------------------------------------------------------------
// k1: conv 1->4 + relu + maxpool2 as MFMA 32x32x16 (pool folded into M).
//     obs (256,1,256,256) f32 -> s1cl [img][16384 px][4ch] f16.
// block: 1 img x 16 pooled rows. LDS: 36 rows x 264 cols f16 (obs as f16).
// B-gather: 4x ds_read_b32 (stride-2 windows are only 4B aligned).
// ---------------------------------------------------------------------------
__global__ __launch_bounds__(256, 4) void k1_mfma(
    const float* __restrict__ obs, const _Float16* __restrict__ wk1F,
    const float* __restrict__ b1, _Float16* __restrict__ s1cl)
{
    __shared__ _Float16 lds[36 * 264];
    u32* ldsu = (u32*)lds;
    int tid = threadIdx.x;
    int lane = tid & 63, w = tid >> 6, g = lane >> 5;
    int yt = blockIdx.x & 7;
    int tb = blockIdx.x >> 3;
    const float* in = obs + ((size_t)tb << 16);

    f16x8 wk1[3];
    #pragma unroll
    for (int q = 0; q < 3; ++q)
        wk1[q] = *(const f16x8*)(wk1F + ((size_t)q * 64 + lane) * 8);
    float bA = b1[g], bB = b1[g + 2];

    for (int i = tid; i < 36 * 132; i += 256) ldsu[i] = 0;
    __syncthreads();
    for (int i = tid; i < 36 * 64; i += 256) {
        int r = i >> 6, c4 = i & 63;
        int gy = (yt << 5) - 2 + r;
        if ((unsigned)gy < 256u) {
            float4 v = *(const float4*)(in + (gy << 8) + (c4 << 2));
            union { _Float16 h[2]; u32 u; } p0, p1;
            p0.h[0] = (_Float16)v.x; p0.h[1] = (_Float16)v.y;
            p1.h[0] = (_Float16)v.z; p1.h[1] = (_Float16)v.w;
            int ui = r * 132 + 1 + 2 * c4;            // f16 col 2+4*c4
            ldsu[ui]     = p0.u;
            ldsu[ui + 1] = p1.u;
        }
    }
    __syncthreads();

    int y0 = yt << 4;
    #pragma unroll
    for (int i = 0; i < 16; ++i) {
        int py_loc = (w << 2) + (i >> 2);             // 0..15
        int px0 = (i & 3) << 5;
        int n = px0 + (lane & 31);                    // pixel col 0..127
        const u32* lp = ldsu + (2 * py_loc + g) * 132 + n;

        f32x16 acc;
        #pragma unroll
        for (int r = 0; r < 16; ++r) acc[r] = 0.f;

        #pragma unroll
        for (int q = 0; q < 3; ++q) {                 // pr = 2q+g (rows 0..5)
            union { f16x8 v; u32 u[4]; } bb;
            const u32* p = lp + (2 * q) * 132;
            bb.u[0] = p[0]; bb.u[1] = p[1]; bb.u[2] = p[2]; bb.u[3] = p[3];
            acc = __builtin_amdgcn_mfma_f32_32x32x16_f16(wk1[q], bb.v, acc, 0, 0, 0);
        }

        float mA = fmaxf(fmaxf(fmaxf(acc[0], acc[1]), fmaxf(acc[2], acc[3])) + bA, 0.f);
        float mB = fmaxf(fmaxf(fmaxf(acc[4], acc[5]), fmaxf(acc[6], acc[7])) + bB, 0.f);

        int pix = ((y0 + py_loc) << 7) + n;
        _Float16* dst = s1cl + (((size_t)tb << 14) + pix) * 4;
        dst[g]     = (_Float16)mA;
        dst[g + 2] = (_Float16)mB;
    }
}

// ---------------------------------------------------------------------------
// k2: conv 4->4 + relu + maxpool2 as MFMA (pool folded into M). Unchanged.
// ---------------------------------------------------------------------------
__global__ __launch_bounds__(256) void k2_mfma(
    const _Float16* __restrict__ s1cl, const _Float16* __restrict__ w2F,
    const float* __restrict__ b2, _Float16* __restrict__ s2cl)
{
    __shared__ _Float16 lds[20 * 136 * 4];
    int tid = threadIdx.x;
    int lane = tid & 63, w = tid >> 6, g = lane >> 5;
    int f  = blockIdx.x >> 3;
    int yt = blockIdx.x & 7;
    int y0 = yt << 3;

    f16x8 wf[12];
    #pragma unroll
    for (int q = 0; q < 12; ++q)
        wf[q] = *(const f16x8*)(w2F + ((size_t)q * 64 + lane) * 8);

    float bA = b2[g], bB = b2[g + 2];

    for (int i = tid; i < 20 * 68; i += 256) {
        int r = i / 68, u = i % 68;
        int gy = (yt << 4) - 2 + r;
        int gx = 2 * u - 2;
        f16x8 v = f16x8_zero();
        if ((unsigned)gy < 128u && (unsigned)gx < 127u)
            v = *(const f16x8*)(s1cl + ((((size_t)f << 14) + (gy << 7) + gx) << 2));
        *(f16x8*)&lds[(r * 136 + 2 * u) * 4] = v;
    }
    __syncthreads();

    #pragma unroll
    for (int i = 0; i < 4; ++i) {
        int ct = w * 4 + i;
        int ly = ct >> 1, hx = ct & 1;
        int px = hx * 32 + (lane & 31);
        int base = (2 * ly) * 1088 + (2 * px) * 8 + g * 16;

        f32x16 acc;
        #pragma unroll
        for (int r = 0; r < 16; ++r) acc[r] = 0.f;

        #pragma unroll
        for (int q = 0; q < 12; ++q) {
            f16x8 bv = *(const f16x8*)((const char*)lds + base +
                                       ((q >> 1) * 1088 + (q & 1) * 32));
            acc = __builtin_amdgcn_mfma_f32_32x32x16_f16(wf[q], bv, acc, 0, 0, 0);
        }

        float mA = fmaxf(fmaxf(fmaxf(acc[0], acc[1]), fmaxf(acc[2], acc[3])) + bA, 0.f);
        float mB = fmaxf(fmaxf(fmaxf(acc[4], acc[5]), fmaxf(acc[6], acc[7])) + bB, 0.f);

        int pix = ((y0 + ly) << 6) + px;
        _Float16* dst = s2cl + ((((size_t)f << 12) + pix) << 2);
        dst[g]     = (_Float16)mA;
        dst[g + 2] = (_Float16)mB;
    }
}

// ---------------------------------------------------------------------------
// k3: conv 4->32 gate precompute, MFMA -> xg f16 fragment layout. Unchanged.
// ---------------------------------------------------------------------------
__global__ __launch_bounds__(256) void k3_mfma(
    const _Float16* __restrict__ s2cl, const _Float16* __restrict__ wxF,
    const float* __restrict__ btot, _Float16* __restrict__ xg)
{
    __shared__ _Float16 lds[12 * 72 * 4];
    int tid = threadIdx.x;
    int lane = tid & 63, w = tid >> 6, g = lane >> 5;
    int f  = blockIdx.x >> 3;
    int yt = blockIdx.x & 7;
    int y0 = yt << 3;

    f16x8 wf[10];
    #pragma unroll
    for (int q = 0; q < 10; ++q)
        wf[q] = *(const f16x8*)(wxF + ((size_t)q * 64 + lane) * 8);

    float bsel[16];
    #pragma unroll
    for (int r = 0; r < 16; ++r) {
        int row0 = (r & 3) + 8 * (r >> 2);
        bsel[r] = g ? btot[row0 + 4] : btot[row0];
    }

    for (int i = tid; i < 12 * 36; i += 256) {
        int r = i / 36, u = i % 36;
        int gy = y0 - 2 + r;
        int gx = 2 * u - 2;
        f16x8 v = f16x8_zero();
        if ((unsigned)gy < 64u && (unsigned)gx < 63u)
            v = *(const f16x8*)(s2cl + ((((size_t)f << 12) + (gy << 6) + gx) << 2));
        *(f16x8*)&lds[(r * 72 + 2 * u) * 4] = v;
    }
    __syncthreads();

    #pragma unroll
    for (int i = 0; i < 4; ++i) {
        int ct = w * 4 + i;
        int ly = ct >> 1, hx = ct & 1;
        int px = hx * 32 + (lane & 31);
        int base = ly * 576 + px * 8 + g * 16;

        f32x16 acc;
        #pragma unroll
        for (int r = 0; r < 16; ++r) acc[r] = 0.f;

        #pragma unroll
        for (int q = 0; q < 10; ++q) {
            f16x8 bv = *(const f16x8*)((const char*)lds + base +
                                       ((q >> 1) * 576 + (q & 1) * 32));
            acc = __builtin_amdgcn_mfma_f32_32x32x16_f16(wf[q], bv, acc, 0, 0, 0);
        }

        size_t tl = (size_t)f * 128 + (y0 + ly) * 2 + hx;
        f16x8 lo, hi;
        #pragma unroll
        for (int r = 0; r < 8; ++r) {
            lo[r] = (_Float16)(acc[r] + bsel[r]);
            hi[r] = (_Float16)(acc[r + 8] + bsel[r + 8]);
        }
        _Float16* dst = xg + tl * 1024 + lane * 16;
        *(f16x8*)dst       = lo;
        *(f16x8*)(dst + 8) = hi;
    }
}

// ---------------------------------------------------------------------------
// k4v2: one ConvLSTM step (multi-launch; launch boundary = device barrier).
//  - c in fragment-layout f32 cfr[tl][lane][4] (coalesced 16B, in-place)
//  - h ping-pong f16 [pix][ch'] with ch' = cc+4g -> single 8B store
//    (whF j-order matches, see kT_prep)
//  - xg/c/peephole loads issued BEFORE LDS staging (latency overlap)
// ---------------------------------------------------------------------------
__global__ __launch_bounds__(256, 4) void k4v2(
    const _Float16* __restrict__ xg_t, const _Float16* __restrict__ hprev,
    const _Float16* __restrict__ whF, float* __restrict__ cfr,
    const float* __restrict__ wci, const float* __restrict__ wcf,
    const float* __restrict__ wco, _Float16* __restrict__ hnext,
    float* __restrict__ out_hc, int last)
{
    __shared__ _Float16 lds[6 * 68 * 8];     // pitch 1088 B/row
    int tid = threadIdx.x;
    int lane = tid & 63, w = tid >> 6, g = lane >> 5;
    int b  = blockIdx.x >> 5;
    int y0 = (blockIdx.x & 31) << 1;

    int ly = w >> 1, hx = w & 1;
    int px = hx * 32 + (lane & 31);
    int pix = ((y0 + ly) << 6) + px;
    size_t tl = (size_t)b * 128 + (y0 + ly) * 2 + hx;

    // ---- early independent global loads (overlap with staging below) ----
    const f16x8* xs = (const f16x8*)(xg_t + tl * 1024 + (size_t)lane * 16);
    f16x8 xv0 = xs[0], xv1 = xs[1];
    float4 cv = *(const float4*)(cfr + tl * 256 + lane * 4);
    float pci[4], pcf[4], pco[4];
    #pragma unroll
    for (int cc = 0; cc < 4; ++cc) {
        int ppix = ((2 * cc + g) << 12) + pix;
        pci[cc] = wci[ppix];
        pcf[cc] = wcf[ppix];
        pco[cc] = wco[ppix];
    }
    f16x8 wf[14];
    #pragma unroll
    for (int q = 0; q < 14; ++q)
        wf[q] = *(const f16x8*)(whF + ((size_t)q * 64 + lane) * 8);

    int toffs[14];
    #pragma unroll
    for (int q = 0; q < 14; ++q) {
        int t0 = 2 * q, t1 = 2 * q + 1;
        int o0 = TKY(t0) * 1088 + TKX(t0) * 16;
        int o1 = TKY(t1) * 1088 + TKX(t1) * 16;
        toffs[q] = g ? o1 : o0;
    }

    // ---- stage h tile (rows y0-2..y0+3, cols -2..65) ----
    for (int i = tid; i < 6 * 68; i += 256) {
        int r = i / 68, u = i % 68;
        int gy = y0 - 2 + r;
        int gx = u - 2;
        f16x8 v = f16x8_zero();
        if ((unsigned)gy < 64u && (unsigned)gx < 64u)
            v = *(const f16x8*)(hprev + ((((size_t)b << 12) + (gy << 6) + gx) << 3));
        *(f16x8*)&lds[(r * 68 + u) * 8] = v;
    }
    __syncthreads();

    f32x16 acc;
    #pragma unroll
    for (int r = 0; r < 8; ++r) {
        acc[r]     = (float)xv0[r];
        acc[r + 8] = (float)xv1[r];
    }

    int base = ly * 1088 + px * 16;
    #pragma unroll
    for (int q = 0; q < 14; ++q) {
        f16x8 bv = *(const f16x8*)((const char*)lds + base + toffs[q]);
        acc = __builtin_amdgcn_mfma_f32_32x32x16_f16(wf[q], bv, acc, 0, 0, 0);
    }

    float cvv[4] = {cv.x, cv.y, cv.z, cv.w};
    float cn4[4];
    f16x4 hv;
    #pragma unroll
    for (int cc = 0; cc < 4; ++cc) {
        float c_old = cvv[cc];
        float i_ = fast_sigmoid(acc[4 * cc + 0] + c_old * pci[cc]);
        float f_ = fast_sigmoid(acc[4 * cc + 1] + c_old * pcf[cc]);
        float cn = f_ * c_old + i_ * fast_tanh(acc[4 * cc + 2]);
        float o_ = fast_sigmoid(acc[4 * cc + 3] + cn * pco[cc]);
        float hn = o_ * fast_tanh(cn);
        cn4[cc] = cn;
        hv[cc] = (_Float16)hn;
        if (last) {
            int ch = 2 * cc + g;
            size_t sidx = (((size_t)b * 8 + ch) << 12) + pix;
            out_hc[sidx] = hn;
            out_hc[sidx + 1048576] = cn;
        }
    }
    if (!last) {
        *(float4*)(cfr + tl * 256 + lane * 4) =
            make_float4(cn4[0], cn4[1], cn4[2], cn4[3]);
        *(f16x4*)(hnext + ((((size_t)b << 12) + pix) << 3) + 4 * g) = hv;
    }
}

// ---------------------------------------------------------------------------
extern "C" void kernel_launch(void* const* d_in, const int* in_sizes, int n_in,
                              void* d_out, int out_size, void* d_ws, size_t ws_size,
                              hipStream_t stream)
{
    const float* obs = (const float*)d_in[0];
    const float* w1  = (const float*)d_in[1];
    const float* b1  = (const float*)d_in[2];
    const float* w2  = (const float*)d_in[3];
    const float* b2  = (const float*)d_in[4];
    const float* wx  = (const float*)d_in[5];
    const float* bx  = (const float*)d_in[6];
    const float* wh  = (const float*)d_in[7];
    const float* bh  = (const float*)d_in[8];
    const float* wci = (const float*)d_in[9];
    const float* wcf = (const float*)d_in[10];
    const float* wco = (const float*)d_in[11];

    char* wsb = (char*)d_ws;
    // byte layout:
    //   [0, 67,108,864)             xg f16 (overlays s1cl, dead after k2)
    //   [67,108,864, 75,497,472)    s2cl f16 [256][4096][4]
    //   [75,497,472, 79,691,776)    hA | hB f16 (1,048,576 f16 each)
    //   [79,691,776, 83,886,080)    cfr f32 [4096 tl][64 lane][4]
    //   [83,886,080, ...)           w2F, wxF, whF, wk1F, btot
    _Float16* xg   = (_Float16*)wsb;
    _Float16* s1cl = (_Float16*)wsb;
    _Float16* s2cl = (_Float16*)(wsb + 67108864);
    _Float16* hA   = (_Float16*)(wsb + 75497472);
    _Float16* hB   = (_Float16*)(wsb + 77594624);
    float*    cfr  = (float*)(wsb + 79691776);
    _Float16* w2F  = (_Float16*)(wsb + 83886080);
    _Float16* wxF  = (_Float16*)(wsb + 83898368);
    _Float16* whF  = (_Float16*)(wsb + 83908608);
    _Float16* wk1F = (_Float16*)(wsb + 83922944);
    float*    btot = (float*)(wsb + 83927040);

    kT_prep<<<64, 256, 0, stream>>>(w1, w2, wx, wh, bx, bh,
                                    wk1F, w2F, wxF, whF, btot, cfr, hA);

    k1_mfma<<<2048, 256, 0, stream>>>(obs, wk1F, b1, s1cl);
    k2_mfma<<<2048, 256, 0, stream>>>(s1cl, w2F, b2, s2cl);
    k3_mfma<<<2048, 256, 0, stream>>>(s2cl, wxF, btot, xg);

    float* outp = (float*)d_out;
    for (int t = 0; t < 8; ++t) {
        const _Float16* hp = (t & 1) ? hB : hA;
        _Float16*       hn = (t & 1) ? hA : hB;
        k4v2<<<1024, 256, 0, stream>>>(
            xg + (size_t)t * 4194304, hp, whF, cfr,
            wci, wcf, wco, hn, outp, t == 7);
    }
}